// Round 2
// baseline (437.346 us; speedup 1.0000x reference)
//
#include <hip/hip_runtime.h>
#include <hip/hip_cooperative_groups.h>
#include <math.h>

namespace cg = cooperative_groups;

// HW exp2 (v_exp_f32) when available.
#if defined(__has_builtin)
#  if __has_builtin(__builtin_amdgcn_exp2f)
#    define EXP2F(x) __builtin_amdgcn_exp2f(x)
#  endif
#endif
#ifndef EXP2F
#  define EXP2F(x) __expf(0.69314718055994530942f * (x))
#endif

// Full-rate-VALU exp2: magic-constant round-to-nearest, deg-3 Taylor on
// f in [-0.5,0.5] (rel err <= 6e-4), exponent rebuilt via (y_int<<23)+p_int.
// Valid for |n| < 512; here arg in [-8, 37]. ~8 full-rate ops, no trans pipe.
__device__ __forceinline__ float fast_exp2(float x) {
  const float M = 12582912.0f;             // 1.5 * 2^23
  const float y = x + M;                   // RNE(x) encoded in mantissa
  const float n = y - M;
  const float f = x - n;                   // [-0.5, 0.5]
  float p = fmaf(f, 0.055504109f, 0.24022651f);
  p = fmaf(f, p, 0.69314718f);
  p = fmaf(f, p, 1.0f);                    // 2^f
  const int r = (__float_as_int(y) << 23) + __float_as_int(p);
  return __int_as_float(r);
}

// R5 theory: R3 (occupancy) and R4 (LDS staging + W prefetch) were BOTH
// neutral -> the inner loop is not the dominant cost. Issue-model floor for
// all 4 layers is ~25-35 us vs 124 us measured, and no layer kernel ever
// cracks the 40-us top-5 bar. Remaining candidate: 4 graph-node launches +
// 3 full inter-kernel drain bubbles. This round fuses all layers into ONE
// cooperative kernel with grid.sync() between layers; inner math identical
// to R4 (single-variable experiment).
template <int IN, int OUT, int BB, bool FIRST>
__device__ __forceinline__ void layer_body(const float* __restrict__ hin,
                                           const float* __restrict__ W,
                                           const float* __restrict__ tau_ptr,
                                           float* __restrict__ hout,
                                           float tau_floor,
                                           float4* __restrict__ lds_h) {
  constexpr int OBB = 2;                 // outputs per 16-lane group
  constexpr int NIT = IN / 64;           // 16 lanes x float4 per iter
  constexpr int nOT = OUT / 32;          // 4 waves x 8 outputs per block
  constexpr int IN4 = IN / 4;            // row length in float4
  constexpr int TILES = nOT * (128 / BB);

  const int tid  = threadIdx.x;
  const int lane = tid & 63;
  const int wid  = tid >> 6;
  const int il   = lane & 15;            // i-lane within group
  const int og   = lane >> 4;            // o-group 0..3

  const float ta  = tau_ptr[0];
  const float tau = tau_floor + (ta >= 0.0f ? ta : 0.05f * ta);
  const float c2  = tau * 1.44269504088896340736f;  // tau * log2(e)
  const float inv_c2 = 1.0f / c2;

  const float4* __restrict__ Wv = (const float4*)W;
  const float4* __restrict__ Hv = (const float4*)hin;

  // Grid-stride over tiles: correct for any co-resident grid size.
  for (int tile = blockIdx.x; tile < TILES; tile += gridDim.x) {
    const int ot = tile % nOT;
    const int bt = tile / nOT;
    const int b0 = bt * BB;
    const int o0 = ot * 32 + wid * 8 + og * OBB;

    __syncthreads();                     // lds_h safe to overwrite
    if (FIRST) {
      // hin is x: (128, IN/2); h = concat(x, 1-x).
      constexpr int HALF4 = IN / 8;
      for (int idx = tid; idx < BB * HALF4; idx += 256) {
        const int r = idx / HALF4;
        const int k = idx - r * HALF4;
        const float4 v = Hv[(b0 + r) * HALF4 + k];
        lds_h[r * IN4 + k] = v;
        lds_h[r * IN4 + HALF4 + k] =
            make_float4(1.0f - v.x, 1.0f - v.y, 1.0f - v.z, 1.0f - v.w);
      }
    } else {
      for (int idx = tid; idx < BB * IN4; idx += 256) {
        const int r = idx / IN4;
        const int k = idx - r * IN4;
        lds_h[r * IN4 + k] = Hv[(b0 + r) * IN4 + k];
      }
    }
    __syncthreads();

    float s[BB][OBB], t[BB][OBB];
#pragma unroll
    for (int r = 0; r < BB; ++r)
#pragma unroll
      for (int c = 0; c < OBB; ++c) { s[r][c] = 0.0f; t[r][c] = 0.0f; }

    // W stream: software pipeline, prefetch distance = 1 ic iteration.
    const float4* wp0 = Wv + (size_t)(o0 + 0) * IN4 + il;
    const float4* wp1 = Wv + (size_t)(o0 + 1) * IN4 + il;
    float4 wcur0 = wp0[0];
    float4 wcur1 = wp1[0];

#pragma unroll 2
    for (int ic = 0; ic < NIT; ++ic) {
      const int icn = (ic + 1 < NIT) ? (ic + 1) : (NIT - 1);
      const float4 wnxt0 = wp0[icn * 16];
      const float4 wnxt1 = wp1[icn * 16];

      float hc[BB][4];
#pragma unroll
      for (int r = 0; r < BB; ++r) {
        const float4 v = lds_h[r * IN4 + ic * 16 + il];
        hc[r][0] = v.x; hc[r][1] = v.y; hc[r][2] = v.z; hc[r][3] = v.w;
      }

      float cw[OBB][4];
      {
        const float wj0[4] = {wcur0.x, wcur0.y, wcur0.z, wcur0.w};
        const float wj1[4] = {wcur1.x, wcur1.y, wcur1.z, wcur1.w};
#pragma unroll
        for (int j = 0; j < 4; ++j) {
          float m  = fminf(fmaxf(wj0[j], 0.0f), 1.0f);      // med3 clamp
          cw[0][j] = c2 * fmaf(0.1f, wj0[j] - m, m);        // leaky outside
          m        = fminf(fmaxf(wj1[j], 0.0f), 1.0f);
          cw[1][j] = c2 * fmaf(0.1f, wj1[j] - m, m);
        }
      }

#pragma unroll
      for (int r = 0; r < BB; ++r)
#pragma unroll
        for (int c = 0; c < OBB; ++c)
#pragma unroll
          for (int j = 0; j < 4; ++j) {
            const float arg = cw[c][j] * hc[r][j];
            // Hybrid: even j on the trans pipe, odd j full-rate.
            const float e = (j & 1) ? fast_exp2(arg) : EXP2F(arg);
            s[r][c] += e;
            t[r][c]  = fmaf(arg, e, t[r][c]);
          }

      wcur0 = wnxt0;
      wcur1 = wnxt1;
    }

    // Reduce partials across the 16 i-lanes of each group.
#pragma unroll
    for (int m = 1; m < 16; m <<= 1)
#pragma unroll
      for (int r = 0; r < BB; ++r)
#pragma unroll
        for (int c = 0; c < OBB; ++c) {
          s[r][c] += __shfl_xor(s[r][c], m, 64);
          t[r][c] += __shfl_xor(t[r][c], m, 64);
        }

    if (il == 0) {
#pragma unroll
      for (int r = 0; r < BB; ++r)
#pragma unroll
        for (int c = 0; c < OBB; ++c) {
          const float out = t[r][c] / s[r][c] * inv_c2;  // sum(z e)/sum(e)
          hout[(b0 + r) * OUT + (o0 + c)] = 1.0f - out;
        }
    }
  }
}

__launch_bounds__(256, 4)
__global__ void fused_net(const float* __restrict__ x,
                          const float* __restrict__ W0, const float* __restrict__ tau0,
                          const float* __restrict__ W1, const float* __restrict__ tau1,
                          const float* __restrict__ W2, const float* __restrict__ tau2,
                          const float* __restrict__ W3, const float* __restrict__ tau3,
                          float* __restrict__ h1, float* __restrict__ h2,
                          float* __restrict__ h3, float* __restrict__ out,
                          float tf0, float tf1, float tf2, float tf3) {
  __shared__ float4 lds_h[1024];         // 16KB, reused by every layer
  cg::grid_group grid = cg::this_grid();

  layer_body<1024, 1024, 4, true >(x,  W0, tau0, h1,  tf0, lds_h);
  __threadfence();                       // h1 visible across XCDs
  grid.sync();
  layer_body<1024,  512, 2, false>(h1, W1, tau1, h2,  tf1, lds_h);
  __threadfence();
  grid.sync();
  layer_body< 512,  256, 1, false>(h2, W2, tau2, h3,  tf2, lds_h);
  __threadfence();
  grid.sync();
  layer_body< 256,  128, 1, false>(h3, W3, tau3, out, tf3, lds_h);
}

// R4 per-layer kernel kept as fallback if cooperative launch is rejected.
template <int IN, int OUT, int BB, bool FIRST>
__launch_bounds__(256, 4)
__global__ void or_layer(const float* __restrict__ hin,
                         const float* __restrict__ W,
                         const float* __restrict__ tau_ptr,
                         float* __restrict__ hout,
                         float tau_floor) {
  __shared__ float4 lds_h[(BB * IN) / 4];
  layer_body<IN, OUT, BB, FIRST>(hin, W, tau_ptr, hout, tau_floor, lds_h);
}

extern "C" void kernel_launch(void* const* d_in, const int* in_sizes, int n_in,
                              void* d_out, int out_size, void* d_ws, size_t ws_size,
                              hipStream_t stream) {
  // setup_inputs() dict order: x, W0, tau0, W1, tau1, W2, tau2, W3, tau3
  const float* x    = (const float*)d_in[0];
  const float* W0   = (const float*)d_in[1];
  const float* tau0 = (const float*)d_in[2];
  const float* W1   = (const float*)d_in[3];
  const float* tau1 = (const float*)d_in[4];
  const float* W2   = (const float*)d_in[5];
  const float* tau2 = (const float*)d_in[6];
  const float* W3   = (const float*)d_in[7];
  const float* tau3 = (const float*)d_in[8];

  float* h1  = (float*)d_ws;        // 128*1024 floats
  float* h2  = h1 + 128 * 1024;     // 128*512
  float* h3  = h2 + 128 * 512;      // 128*256
  float* out = (float*)d_out;       // 128*128

  const double LOGR = 2.9444389791664403;  // log(0.95) - log(0.05) = log(19)
  float tf1024 = (float)(log(1023.0) + LOGR);
  float tf512  = (float)(log(511.0)  + LOGR);
  float tf256  = (float)(log(255.0)  + LOGR);

  // Co-resident grid size for the cooperative launch (cached; host-side
  // query only, graph-capture safe). MI355X: 256 CUs.
  static int nblk = 0;
  if (nblk == 0) {
    int per_cu = 0;
    if (hipOccupancyMaxActiveBlocksPerMultiprocessor(&per_cu, fused_net, 256, 0)
            != hipSuccess || per_cu <= 0)
      per_cu = 1;
    nblk = per_cu * 256;
    if (nblk > 1024) nblk = 1024;    // 1024 tiles is the max any layer has
  }

  void* args[] = {&x,  &W0, &tau0, &W1, &tau1, &W2, &tau2, &W3, &tau3,
                  &h1, &h2, &h3,   &out, &tf1024, &tf1024, &tf512, &tf256};
  hipError_t err = hipLaunchCooperativeKernel(
      fused_net, dim3(nblk), dim3(256), args, 0, stream);

  if (err != hipSuccess) {
    // Fallback: R4 4-kernel path.
    or_layer<1024, 1024, 4, true ><<<1024, 256, 0, stream>>>(x,  W0, tau0, h1,  tf1024);
    or_layer<1024,  512, 2, false><<<1024, 256, 0, stream>>>(h1, W1, tau1, h2,  tf1024);
    or_layer< 512,  256, 1, false><<<1024, 256, 0, stream>>>(h2, W2, tau2, h3,  tf512);
    or_layer< 256,  128, 1, false><<< 512, 256, 0, stream>>>(h3, W3, tau3, out, tf256);
  }
}

// Round 3
// 148.362 us; speedup vs baseline: 2.9478x; 2.9478x over previous
//
#include <hip/hip_runtime.h>
#include <math.h>

// HW exp2 (v_exp_f32) when available.
#if defined(__has_builtin)
#  if __has_builtin(__builtin_amdgcn_exp2f)
#    define EXP2F(x) __builtin_amdgcn_exp2f(x)
#  endif
#endif
#ifndef EXP2F
#  define EXP2F(x) __expf(0.69314718055994530942f * (x))
#endif

// Full-rate-VALU exp2: magic-constant round-to-nearest, deg-3 Taylor on
// f in [-0.5,0.5] (rel err <= 6e-4), exponent rebuilt via (y_int<<23)+p_int.
// Valid for |n| < 512; here arg in [-8, 37]. ~8 full-rate ops, no trans pipe.
__device__ __forceinline__ float fast_exp2(float x) {
  const float M = 12582912.0f;             // 1.5 * 2^23
  const float y = x + M;                   // RNE(x) encoded in mantissa
  const float n = y - M;
  const float f = x - n;                   // [-0.5, 0.5]
  float p = fmaf(f, 0.055504109f, 0.24022651f);
  p = fmaf(f, p, 0.69314718f);
  p = fmaf(f, p, 1.0f);                    // 2^f
  const int r = (__float_as_int(y) << 23) + __float_as_int(p);
  return __int_as_float(r);
}

// R6: R5 proved (a) total VALU work is only ~35-40 us (VALUBusy 5.9% x 656 us),
// (b) cg::grid.sync() costs ~150-200 us per sync on a 1024-block grid -> the
// 124-us baseline is dominated by per-kernel fixed costs (4 launches + 3 drain
// bubbles), not the inner loop. This round: 4 -> 2 dispatches with NO grid
// sync. K1 = layer 0 (validated R4 kernel). K2 = layers 1-3 fused, one block
// per batch row, layer boundaries via __syncthreads, h2/h3 in LDS. Inner math
// identical to the 124-us-validated hybrid-exp path.

// ---------------- K1: layer 0 (R4 kernel, unchanged) ----------------
template <int IN, int OUT, int BB, bool FIRST>
__launch_bounds__(256, 4)
__global__ void or_layer(const float* __restrict__ hin,
                         const float* __restrict__ W,
                         const float* __restrict__ tau_ptr,
                         float* __restrict__ hout,
                         float tau_floor) {
  constexpr int OBB = 2;                 // outputs per 16-lane group
  constexpr int NIT = IN / 64;           // 16 lanes x float4 per iter
  constexpr int nOT = OUT / 32;          // 4 waves x 8 outputs per block
  constexpr int IN4 = IN / 4;            // row length in float4

  __shared__ float4 lds_h[BB * IN4];

  const int tid  = threadIdx.x;
  const int lane = tid & 63;
  const int wid  = tid >> 6;
  const int il   = lane & 15;            // i-lane within group
  const int og   = lane >> 4;            // o-group 0..3

  const int ot = blockIdx.x % nOT;
  const int bt = blockIdx.x / nOT;
  const int b0 = bt * BB;
  const int o0 = ot * 32 + wid * 8 + og * OBB;

  const float ta  = tau_ptr[0];
  const float tau = tau_floor + (ta >= 0.0f ? ta : 0.05f * ta);
  const float c2  = tau * 1.44269504088896340736f;  // tau * log2(e)

  const float4* __restrict__ Wv = (const float4*)W;
  const float4* __restrict__ Hv = (const float4*)hin;

  if (FIRST) {
    // hin is x: (128, IN/2); h = concat(x, 1-x).
    constexpr int HALF4 = IN / 8;
    for (int idx = tid; idx < BB * HALF4; idx += 256) {
      const int r = idx / HALF4;
      const int k = idx - r * HALF4;
      const float4 v = Hv[(b0 + r) * HALF4 + k];
      lds_h[r * IN4 + k] = v;
      lds_h[r * IN4 + HALF4 + k] =
          make_float4(1.0f - v.x, 1.0f - v.y, 1.0f - v.z, 1.0f - v.w);
    }
  } else {
    for (int idx = tid; idx < BB * IN4; idx += 256) {
      const int r = idx / IN4;
      const int k = idx - r * IN4;
      lds_h[r * IN4 + k] = Hv[(b0 + r) * IN4 + k];
    }
  }
  __syncthreads();

  float s[BB][OBB], t[BB][OBB];
#pragma unroll
  for (int r = 0; r < BB; ++r)
#pragma unroll
    for (int c = 0; c < OBB; ++c) { s[r][c] = 0.0f; t[r][c] = 0.0f; }

  const float4* wp0 = Wv + (size_t)(o0 + 0) * IN4 + il;
  const float4* wp1 = Wv + (size_t)(o0 + 1) * IN4 + il;
  float4 wcur0 = wp0[0];
  float4 wcur1 = wp1[0];

#pragma unroll 2
  for (int ic = 0; ic < NIT; ++ic) {
    const int icn = (ic + 1 < NIT) ? (ic + 1) : (NIT - 1);
    const float4 wnxt0 = wp0[icn * 16];
    const float4 wnxt1 = wp1[icn * 16];

    float hc[BB][4];
#pragma unroll
    for (int r = 0; r < BB; ++r) {
      const float4 v = lds_h[r * IN4 + ic * 16 + il];
      hc[r][0] = v.x; hc[r][1] = v.y; hc[r][2] = v.z; hc[r][3] = v.w;
    }

    float cw[OBB][4];
    {
      const float wj0[4] = {wcur0.x, wcur0.y, wcur0.z, wcur0.w};
      const float wj1[4] = {wcur1.x, wcur1.y, wcur1.z, wcur1.w};
#pragma unroll
      for (int j = 0; j < 4; ++j) {
        float m  = fminf(fmaxf(wj0[j], 0.0f), 1.0f);      // med3 clamp
        cw[0][j] = c2 * fmaf(0.1f, wj0[j] - m, m);        // leaky outside
        m        = fminf(fmaxf(wj1[j], 0.0f), 1.0f);
        cw[1][j] = c2 * fmaf(0.1f, wj1[j] - m, m);
      }
    }

#pragma unroll
    for (int r = 0; r < BB; ++r)
#pragma unroll
      for (int c = 0; c < OBB; ++c)
#pragma unroll
        for (int j = 0; j < 4; ++j) {
          const float arg = cw[c][j] * hc[r][j];
          // Hybrid: even j on the trans pipe, odd j full-rate.
          const float e = (j & 1) ? fast_exp2(arg) : EXP2F(arg);
          s[r][c] += e;
          t[r][c]  = fmaf(arg, e, t[r][c]);
        }

    wcur0 = wnxt0;
    wcur1 = wnxt1;
  }

#pragma unroll
  for (int m = 1; m < 16; m <<= 1)
#pragma unroll
    for (int r = 0; r < BB; ++r)
#pragma unroll
      for (int c = 0; c < OBB; ++c) {
        s[r][c] += __shfl_xor(s[r][c], m, 64);
        t[r][c] += __shfl_xor(t[r][c], m, 64);
      }

  if (il == 0) {
    const float inv_c2 = 1.0f / c2;
#pragma unroll
    for (int r = 0; r < BB; ++r)
#pragma unroll
      for (int c = 0; c < OBB; ++c) {
        const float out = t[r][c] / s[r][c] * inv_c2;  // sum(z e)/sum(e)
        hout[(b0 + r) * OUT + (o0 + c)] = 1.0f - out;
      }
  }
}

// ---------------- K2: layers 1-3 fused, one block per batch row ----------------
// 1024 threads = 64 groups of 16 lanes; group g owns OUT/64 outputs.
// Input tile and all intermediates live in LDS; only W streams from L2.
template <int IN, int OUT, bool LAST>
__device__ __forceinline__ void sub_layer(const float4* __restrict__ in4,
                                          const float* __restrict__ W,
                                          const float* __restrict__ tau_ptr,
                                          float tau_floor,
                                          float* __restrict__ out_lds,
                                          float* __restrict__ out_glob) {
  constexpr int NIT = IN / 64;           // 16 lanes x float4
  constexpr int IN4 = IN / 4;
  constexpr int OPG = OUT / 64;          // outputs per 16-lane group

  const int tid = threadIdx.x;
  const int il  = tid & 15;
  const int g   = tid >> 4;              // 0..63, groups wave-aligned

  const float ta  = tau_ptr[0];
  const float tau = tau_floor + (ta >= 0.0f ? ta : 0.05f * ta);
  const float c2  = tau * 1.44269504088896340736f;
  const float inv_c2 = 1.0f / c2;

  const float4* __restrict__ Wv = (const float4*)W;

#pragma unroll
  for (int ob = 0; ob < OPG / 2; ++ob) {
    const int o0 = g * OPG + ob * 2;
    float s0 = 0.0f, s1 = 0.0f, t0 = 0.0f, t1 = 0.0f;

#pragma unroll 2
    for (int ic = 0; ic < NIT; ++ic) {
      const float4 hv = in4[ic * 16 + il];               // broadcast in-wave
      const float4 w0 = Wv[(size_t)(o0 + 0) * IN4 + ic * 16 + il];
      const float4 w1 = Wv[(size_t)(o0 + 1) * IN4 + ic * 16 + il];
      const float h[4] = {hv.x, hv.y, hv.z, hv.w};
      const float a[4] = {w0.x, w0.y, w0.z, w0.w};
      const float b[4] = {w1.x, w1.y, w1.z, w1.w};
#pragma unroll
      for (int j = 0; j < 4; ++j) {
        float m = fminf(fmaxf(a[j], 0.0f), 1.0f);        // med3 clamp
        const float ca = c2 * fmaf(0.1f, a[j] - m, m);   // leaky outside
        m = fminf(fmaxf(b[j], 0.0f), 1.0f);
        const float cb = c2 * fmaf(0.1f, b[j] - m, m);
        const float arga = ca * h[j];
        const float argb = cb * h[j];
        const float ea = (j & 1) ? fast_exp2(arga) : EXP2F(arga);
        const float eb = (j & 1) ? fast_exp2(argb) : EXP2F(argb);
        s0 += ea; t0 = fmaf(arga, ea, t0);
        s1 += eb; t1 = fmaf(argb, eb, t1);
      }
    }

#pragma unroll
    for (int m = 1; m < 16; m <<= 1) {
      s0 += __shfl_xor(s0, m, 64); t0 += __shfl_xor(t0, m, 64);
      s1 += __shfl_xor(s1, m, 64); t1 += __shfl_xor(t1, m, 64);
    }

    if (il == 0) {
      const float r0 = 1.0f - t0 / s0 * inv_c2;          // invert
      const float r1 = 1.0f - t1 / s1 * inv_c2;
      if (LAST) { out_glob[o0] = r0; out_glob[o0 + 1] = r1; }
      else      { out_lds[o0]  = r0; out_lds[o0 + 1]  = r1; }
    }
  }
}

__launch_bounds__(1024)
__global__ void fused_tail(const float* __restrict__ h1,
                           const float* __restrict__ W1, const float* __restrict__ tau1,
                           const float* __restrict__ W2, const float* __restrict__ tau2,
                           const float* __restrict__ W3, const float* __restrict__ tau3,
                           float* __restrict__ out,
                           float tf_a, float tf_b, float tf_c) {
  __shared__ float4 hA[256];             // 1024 floats (h1 row)
  __shared__ float4 hB[128];             // 512 floats  (h2 row)
  __shared__ float4 hC[64];              // 256 floats  (h3 row)

  const int row = blockIdx.x;
  const int tid = threadIdx.x;

  if (tid < 256) hA[tid] = ((const float4*)h1)[row * 256 + tid];
  __syncthreads();

  sub_layer<1024, 512, false>(hA, W1, tau1, tf_a, (float*)hB, nullptr);
  __syncthreads();
  sub_layer< 512, 256, false>(hB, W2, tau2, tf_b, (float*)hC, nullptr);
  __syncthreads();
  sub_layer< 256, 128, true >(hC, W3, tau3, tf_c, nullptr, out + row * 128);
}

extern "C" void kernel_launch(void* const* d_in, const int* in_sizes, int n_in,
                              void* d_out, int out_size, void* d_ws, size_t ws_size,
                              hipStream_t stream) {
  // setup_inputs() dict order: x, W0, tau0, W1, tau1, W2, tau2, W3, tau3
  const float* x    = (const float*)d_in[0];
  const float* W0   = (const float*)d_in[1];
  const float* tau0 = (const float*)d_in[2];
  const float* W1   = (const float*)d_in[3];
  const float* tau1 = (const float*)d_in[4];
  const float* W2   = (const float*)d_in[5];
  const float* tau2 = (const float*)d_in[6];
  const float* W3   = (const float*)d_in[7];
  const float* tau3 = (const float*)d_in[8];

  float* h1  = (float*)d_ws;        // 128*1024 floats
  float* out = (float*)d_out;       // 128*128

  const double LOGR = 2.9444389791664403;  // log(0.95) - log(0.05) = log(19)
  const float tf1024 = (float)(log(1023.0) + LOGR);
  const float tf512  = (float)(log(511.0)  + LOGR);
  const float tf256  = (float)(log(255.0)  + LOGR);

  // K1: layer 0 over the full machine (1024 blocks).
  or_layer<1024, 1024, 4, true><<<1024, 256, 0, stream>>>(x, W0, tau0, h1, tf1024);
  // K2: layers 1-3 fused, one block per batch row; boundaries are
  // __syncthreads (cheap), intermediates never leave LDS.
  fused_tail<<<128, 1024, 0, stream>>>(h1, W1, tau1, W2, tau2, W3, tau3,
                                       out, tf1024, tf512, tf256);
}